// Round 10
// baseline (75.073 us; speedup 1.0000x reference)
//
#include <hip/hip_runtime.h>

// Problem constants: B=8, S=1024, E=128, H=32, DK=4.
constexpr int kS = 1024;

typedef __fp16 fp16x2 __attribute__((ext_vector_type(2)));
typedef _Float16 half4v __attribute__((ext_vector_type(4)));
typedef _Float16 half8v __attribute__((ext_vector_type(8)));
typedef float float4v __attribute__((ext_vector_type(4)));
typedef float float16v __attribute__((ext_vector_type(16)));

// ---------------------------------------------------------------------------
// K1: quantum encoder (analytic collapse, verified R1-R8).
// z0=c1c2c3, z1=c0c1, z2=c0c1c2, z3=c0c1c2c3, c_w=cos(x_w + theta_w).
// h16[bh][s][d] = f16(0.25*z_d). attn duplicates dims 4x across the 16
// k-slots (R8 convention) -> ST = 4*(1/16)*z_q.z_k = q.k/4 = u in [-1,1].
// (R9 BUG: stored 0.5*z with {x,y,0,0} fill -> dims hit k-slots 0-3 AND
//  8-11 via the hi-lane halves -> ST = 2u, poly fed out-of-range.)
// hvq[bh][kb(32)][chunk(2)][row(8)][hi(2)][j(8)] f16 (V^T fragments):
//   key = kb*32 + chunk*16 + kappa(hi,j), kappa = (j&3) + 8*(j>>2) + 4*hi.
//   rows 0-3 = z_d UNSCALED, row 4 = 1.0 (denominator), rows 5-7 don't-care.
// ---------------------------------------------------------------------------
__global__ __launch_bounds__(256) void qenc_kernel(
    const float4* __restrict__ x4, const float* __restrict__ qp,
    uint2* __restrict__ h16u, ushort* __restrict__ hvq,
    uint* __restrict__ hvqu) {
  int idx = blockIdx.x * 256 + threadIdx.x;
  float4 a = x4[idx];
  float c0 = cosf(a.x + qp[0]);
  float c1 = cosf(a.y + qp[1]);
  float c2 = cosf(a.z + qp[2]);
  float c3 = cosf(a.w + qp[3]);
  float z1 = c0 * c1;
  float z2 = z1 * c2;
  float z3 = z2 * c3;
  float z0 = c1 * c2 * c3;
  // Q/K copy: 0.25*z (4x slot duplication in attn -> ST = q.k/4)
  union { half4v h; uint2 u; } q;
  q.h.x = (_Float16)(z0 * 0.25f);
  q.h.y = (_Float16)(z1 * 0.25f);
  q.h.z = (_Float16)(z2 * 0.25f);
  q.h.w = (_Float16)(z3 * 0.25f);
  // V copy: unscaled
  union { half4v h; ushort4 us; } v;
  v.h.x = (_Float16)z0;
  v.h.y = (_Float16)z1;
  v.h.z = (_Float16)z2;
  v.h.w = (_Float16)z3;
  int b = idx >> 15;
  int s = (idx >> 5) & (kS - 1);
  int head = idx & 31;
  int bh = b * 32 + head;
  h16u[(bh << 10) + s] = q.u;
  // V^T scatter: key s -> (kb, chunk, hi, j)
  int kb = s >> 5, kk = s & 31;
  int chunk = (kk >> 4) & 1, kk4 = kk & 15;
  int hi = (kk4 >> 2) & 1;
  int j = (kk4 & 3) + ((kk4 >> 3) << 2);
  int base = (bh << 13) + (kb << 8) + (chunk << 7) + (hi << 3) + j;
  hvq[base + 0] = v.us.x;   // row 0
  hvq[base + 16] = v.us.y;  // row 1
  hvq[base + 32] = v.us.z;  // row 2
  hvq[base + 48] = v.us.w;  // row 3
  // row 4 = 1.0: 4 uints per (kb,chunk,hi); threads s<512 cover them.
  if (s < 512) {
    int t = s;
    int ukb = t >> 4, uch = (t >> 3) & 1, uhi = (t >> 2) & 1, m = t & 3;
    hvqu[(bh << 12) + (ukb << 7) + (uch << 6) + 32 + (uhi << 2) + m] =
        0x3C003C00u;
  }
}

// ---------------------------------------------------------------------------
// K2: fused attention, exp-free. mfma_f32_32x32x16_f16; one wave = (bh, 32 q).
// QK^T: dims duplicated 4x across 16 k-slots on both operands (0.25*z stored)
// -> ST = u = q.k/4 in [-1,1] exactly.
// P = e^{2u} via degree-6 Chebyshev poly in PACKED f16 (v_pk_fma): replaces
// 16 v_exp_f32 (~256 cyc/iter pipe occupancy) with 48 pk_fma (~96).
// ST C/D (m74/m101): col=lane&31=q, regs 0-7 = keys kappa(hi,j) chunk 0,
// regs 8-15 = chunk 1 -> PV B-frag for chunk c = poly(cvt(st[8c..8c+7])).
// Both P and V place key 16c+kappa(hi,j) at slot (j,hi): contraction pairs
// matching keys for any hw slot->k bijection. PV A-frag = hvq rows (r&7):
// rows 0-3 V data, row 4 ones (denominator in acc reg0 of hi lanes).
// ---------------------------------------------------------------------------
__global__ __launch_bounds__(256) void attn_kernel(
    const _Float16* __restrict__ h16, const _Float16* __restrict__ hvq,
    uint2* __restrict__ o16u2) {
  const int lane = threadIdx.x & 63;
  const int wv = threadIdx.x >> 6;
  const int job = blockIdx.x * 4 + wv;
  const int bh = job >> 5;
  const int q0 = (job & 31) << 5;
  const int r = lane & 31;
  const int hi = lane >> 5;

  const uint2* __restrict__ hb2 = (const uint2*)(h16) + (bh << 10);
  const uint4* __restrict__ vb4 = (const uint4*)(hvq) + (bh << 10);

  // e^{2u} on u in [-1,1], Chebyshev deg-6 (trunc err ~5e-4 abs):
  const fp16x2 C0 = {(__fp16)0.99995f, (__fp16)0.99995f};
  const fp16x2 C1 = {(__fp16)2.00340f, (__fp16)2.00340f};
  const fp16x2 C2 = {(__fp16)2.00235f, (__fp16)2.00235f};
  const fp16x2 C3 = {(__fp16)1.30842f, (__fp16)1.30842f};
  const fp16x2 C4 = {(__fp16)0.65724f, (__fp16)0.65724f};
  const fp16x2 C5 = {(__fp16)0.31451f, (__fp16)0.31451f};
  const fp16x2 C6 = {(__fp16)0.10240f, (__fp16)0.10240f};

  union U4H { uint4 u; half8v h; };
  U4H uq;
  {
    uint2 qv = hb2[q0 + r];
    uq.u.x = qv.x; uq.u.y = qv.y; uq.u.z = qv.x; uq.u.w = qv.y;
  }

  const int vbase = ((r & 7) << 1) + hi;  // uint4 idx within kb: row*2 + hi

  float16v acc = {};
  const float16v zero = {};

#pragma unroll 2
  for (int k0 = 0; k0 < kS; k0 += 32) {
    U4H uk;
    {
      uint2 kv = hb2[k0 + r];
      uk.u.x = kv.x; uk.u.y = kv.y; uk.u.z = kv.x; uk.u.w = kv.y;
    }
    U4H uv0, uv1;
    uv0.u = vb4[k0 + vbase];
    uv1.u = vb4[k0 + 16 + vbase];
    float16v st =
        __builtin_amdgcn_mfma_f32_32x32x16_f16(uk.h, uq.h, zero, 0, 0, 0);
#define PV_CHUNK(C, UV)                                                      \
  {                                                                          \
    union { fp16x2 p[4]; half8v h; } up;                                     \
    _Pragma("unroll")                                                        \
    for (int m = 0; m < 4; ++m) {                                            \
      fp16x2 u2 = __builtin_amdgcn_cvt_pkrtz(st[8 * C + 2 * m],              \
                                             st[8 * C + 2 * m + 1]);         \
      fp16x2 p = C6 * u2 + C5;  /* -ffp-contract=fast -> v_pk_fma_f16 */     \
      p = p * u2 + C4;                                                       \
      p = p * u2 + C3;                                                       \
      p = p * u2 + C2;                                                       \
      p = p * u2 + C1;                                                       \
      p = p * u2 + C0;                                                       \
      up.p[m] = p;                                                           \
    }                                                                        \
    acc = __builtin_amdgcn_mfma_f32_32x32x16_f16(UV.h, up.h, acc, 0, 0, 0);  \
  }
    PV_CHUNK(0, uv0)
    PV_CHUNK(1, uv1)
#undef PV_CHUNK
  }

  float denom = __shfl_xor(acc[0], 32);  // lanes 0-31 get PV row 4 = sum P
  if (hi == 0) {
    float inv = 1.0f / denom;  // V unscaled: no extra factor
    union { fp16x2 p[2]; uint2 u; } res;
    res.p[0] = __builtin_amdgcn_cvt_pkrtz(acc[0] * inv, acc[1] * inv);
    res.p[1] = __builtin_amdgcn_cvt_pkrtz(acc[2] * inv, acc[3] * inv);
    int b = bh >> 5, head = bh & 31;
    o16u2[(((b << 10) + q0 + r) << 5) + head] = res.u;
  }
}

// ---------------------------------------------------------------------------
// K0: pack W into B-fragment layout wtb[e>>3][col][e&7] (f16) for the
// combine MFMA: B[k=e][col] = W[col][e].
// ---------------------------------------------------------------------------
__global__ __launch_bounds__(256) void wtb_kernel(
    const float* __restrict__ W, _Float16* __restrict__ wtb) {
  int i = blockIdx.x * 256 + threadIdx.x;  // 16384
  int col = i >> 7, e = i & 127;
  wtb[((e >> 3) << 10) + (col << 3) + (e & 7)] = (_Float16)W[i];
}

// ---------------------------------------------------------------------------
// K3: combine GEMM out[8192][128] = o16 @ W^T via mfma_f32_16x16x32_f16.
// One wave per 16x16 tile: 512 row-tiles x 8 col-tiles = 4096 waves.
// (verified R6/R8: ~3 us)
// ---------------------------------------------------------------------------
__global__ __launch_bounds__(256) void combine_kernel(
    const _Float16* __restrict__ o16, const _Float16* __restrict__ wtb,
    float* __restrict__ out) {
  const int lane = threadIdx.x & 63;
  const int wv = threadIdx.x >> 6;
  const int job = blockIdx.x * 4 + wv;  // 0..4095
  const int rt = job >> 3, ct = job & 7;
  const int c = lane & 15, g = lane >> 4;
  const uint4* a4 = (const uint4*)o16;
  const uint4* b4 = (const uint4*)wtb;
  const int arow = (rt << 4) + c;
  union U4H { uint4 u; half8v h; };
  float4v acc = {};
#pragma unroll
  for (int t = 0; t < 4; ++t) {
    U4H ua, ub;
    ua.u = a4[(arow << 4) + (t << 2) + g];
    ub.u = b4[(((t << 2) + g) << 7) + (ct << 4) + c];
    acc = __builtin_amdgcn_mfma_f32_16x16x32_f16(ua.h, ub.h, acc, 0, 0, 0);
  }
  const int orow = (rt << 4) + (g << 2);
  const int ocol = (ct << 4) + c;
#pragma unroll
  for (int reg = 0; reg < 4; ++reg)
    out[(orow + reg) * 128 + ocol] = acc[reg];
}

extern "C" void kernel_launch(void* const* d_in, const int* in_sizes, int n_in,
                              void* d_out, int out_size, void* d_ws,
                              size_t ws_size, hipStream_t stream) {
  const float* x = (const float*)d_in[0];   // [8,1024,128] f32
  const float* qp = (const float*)d_in[1];  // [1,4] f32
  const float* W = (const float*)d_in[2];   // [128,128] f32
  float* out = (float*)d_out;               // [8,1024,128] f32

  char* ws = (char*)d_ws;
  _Float16* h16 = (_Float16*)ws;                // [256][1024][4] f16 = 2 MB
  _Float16* hvq = (_Float16*)(ws + (2 << 20));  // [256][32][2][8][2][8] = 4 MB
  _Float16* o16 = (_Float16*)(ws + (6 << 20));  // [8192][128] f16 = 2 MB
  _Float16* wtb = (_Float16*)(ws + (8 << 20));  // [16][128][8] f16 = 32 KB

  wtb_kernel<<<64, 256, 0, stream>>>(W, wtb);
  qenc_kernel<<<1024, 256, 0, stream>>>((const float4*)x, qp, (uint2*)h16,
                                        (ushort*)hvq, (uint*)hvq);
  attn_kernel<<<2048, 256, 0, stream>>>(h16, hvq, (uint2*)o16);
  combine_kernel<<<1024, 256, 0, stream>>>(o16, wtb, out);
}